// Round 1
// baseline (160.696 us; speedup 1.0000x reference)
//
#include <hip/hip_runtime.h>
#include <hip/hip_bf16.h>

#define K 16
#define Bn 1024
#define Tn 512
#define PAD_ID 0
#define START_ID 14
#define STOP_ID 15
#define CHUNK 64
#define NCH (Tn / CHUNK)   // 8 chunks

typedef float f32x4 __attribute__((ext_vector_type(4)));
typedef short s16x4 __attribute__((ext_vector_type(4)));

// pack 4 floats -> 4 bf16 (RNE) as v4i16 for the mfma operand
static __device__ __forceinline__ s16x4 pack_bf16x4(float a, float b, float c, float d) {
    __hip_bfloat162 lo = __float22bfloat162_rn(float2{a, b});
    __hip_bfloat162 hi = __float22bfloat162_rn(float2{c, d});
    union { __hip_bfloat162 h2[2]; s16x4 v; } u;
    u.h2[0] = lo; u.h2[1] = hi;
    return u.v;
}

// ---------------------------------------------------------------------------
// Phase A: one wave per (sequence b, chunk c). Computes the 16x16 linear-space
// transfer matrix P_c = prod_{t in chunk, valid} (D_t * E) with running log-scale.
// E[j][i] = exp(trans[j][i]); D_t = diag(exp(h[b][t][:])).
// mfma_f32_16x16x16_bf16: A[m=lane&15][k=4q+j], B[k=4q+j][n=lane&15],
// C/D[row=4q+reg][col=lane&15]  -> D feeds back as B with only a cvt.
// ---------------------------------------------------------------------------
__global__ __launch_bounds__(256) void crf_chunk_kernel(
    const float* __restrict__ h, const float* __restrict__ mask,
    const float* __restrict__ trans, float* __restrict__ Pout,
    float* __restrict__ Sout)
{
    int wid  = (blockIdx.x * blockDim.x + threadIdx.x) >> 6;
    int lane = threadIdx.x & 63;
    int b = wid / NCH, c = wid % NCH;
    int j = lane & 15, q = lane >> 4;
    int t0 = c * CHUNK;

    // E fragment (A-operand rows): E[m=j][k=4q+r]
    float E0[4];
#pragma unroll
    for (int r = 0; r < 4; ++r)
        E0[r] = __expf(trans[j * K + (q * 4 + r)]);   // exp(-10000) -> 0 exactly

    // number of valid steps in this chunk (mask is a contiguous prefix)
    float mval = mask[b * Tn + t0 + lane];
    unsigned long long bal = __ballot(mval > 0.5f);
    int nv = __popcll(bal);

    // B fragment starts as identity (bf16 1.0 = 0x3F80)
    s16x4 bfrag;
#pragma unroll
    for (int r = 0; r < 4; ++r)
        ((short*)&bfrag)[r] = (q * 4 + r == j) ? (short)0x3F80 : (short)0;

    // D starts as identity (covers nv==0: P = I, scale = 0)
    f32x4 D;
#pragma unroll
    for (int r = 0; r < 4; ++r) D[r] = (q * 4 + r == j) ? 1.0f : 0.0f;

    float ls = 0.0f;
    const float* hb = h + (size_t)(b * Tn + t0) * K + j;

    for (int ts = 0; ts < nv; ts += 16) {
        // preload 16 steps of emissions for this lane's row m=j
        float ht[16];
#pragma unroll
        for (int r = 0; r < 16; ++r)
            ht[r] = hb[(ts + r) * K];      // stays inside the chunk (ts+r <= 63)

        int n = nv - ts; if (n > 16) n = 16;
#pragma unroll
        for (int r = 0; r < 16; ++r) {
            if (r >= n) break;             // wave-uniform exit
            float d = __expf(ht[r]);
            s16x4 afrag = pack_bf16x4(d * E0[0], d * E0[1], d * E0[2], d * E0[3]);
            D = __builtin_amdgcn_mfma_f32_16x16x16bf16_1k(afrag, bfrag,
                                                          (f32x4){0.f,0.f,0.f,0.f},
                                                          0, 0, 0);
            int t = ts + r;
            if ((t & 3) == 3 || t == nv - 1) {   // rescale: keep max ~ 1
                float m = fmaxf(fmaxf(D[0], D[1]), fmaxf(D[2], D[3]));
#pragma unroll
                for (int off = 1; off < 64; off <<= 1)
                    m = fmaxf(m, __shfl_xor(m, off, 64));
                float inv = 1.0f / m;
                ls += __logf(m);
                D[0] *= inv; D[1] *= inv; D[2] *= inv; D[3] *= inv;
            }
            bfrag = pack_bf16x4(D[0], D[1], D[2], D[3]);
        }
    }

    // store P row-major [row][col] and the log-scale
    float* P = Pout + (size_t)(b * NCH + c) * 256;
#pragma unroll
    for (int r = 0; r < 4; ++r)
        P[(q * 4 + r) * 16 + j] = D[r];
    if (lane == 0) Sout[b * NCH + c] = ls;
}

// ---------------------------------------------------------------------------
// Phase B: one wave per sequence. alpha = e_START; alpha <- P_c * alpha over
// 8 chunks (fp32 matvec with per-chunk renormalization), then
// fwd = ls + log(sum_j alpha[j] * exp(trans[STOP][j])). Atomic-add fwd/B.
// Lane (j = lane&15, q = lane>>4): holds P[b][c][j][4q..4q+3] and alpha[4q..4q+3].
// ---------------------------------------------------------------------------
__global__ __launch_bounds__(256) void crf_combine_kernel(
    const float* __restrict__ Pin, const float* __restrict__ Sin,
    const float* __restrict__ trans, float* __restrict__ out)
{
    int wid  = (blockIdx.x * blockDim.x + threadIdx.x) >> 6;
    int lane = threadIdx.x & 63;
    int b = wid;
    int j = lane & 15, q = lane >> 4;

    f32x4 Prow[NCH];
#pragma unroll
    for (int c = 0; c < NCH; ++c)
        Prow[c] = *(const f32x4*)(Pin + (size_t)(b * NCH + c) * 256 + j * 16 + q * 4);
    float sc[NCH];
#pragma unroll
    for (int c = 0; c < NCH; ++c) sc[c] = Sin[b * NCH + c];

    float ap[4];
#pragma unroll
    for (int r = 0; r < 4; ++r) ap[r] = (q * 4 + r == START_ID) ? 1.0f : 0.0f;
    float ls = 0.0f;

#pragma unroll
    for (int c = 0; c < NCH; ++c) {
        float acc = Prow[c][0]*ap[0] + Prow[c][1]*ap[1]
                  + Prow[c][2]*ap[2] + Prow[c][3]*ap[3];
        acc += __shfl_xor(acc, 16, 64);          // sum over quads: new alpha[j]
        acc += __shfl_xor(acc, 32, 64);
        float m = acc;
#pragma unroll
        for (int off = 1; off < 16; off <<= 1)   // max over j within group
            m = fmaxf(m, __shfl_xor(m, off, 16));
        ls += sc[c] + __logf(m);
        float an = acc * (1.0f / m);
#pragma unroll
        for (int r = 0; r < 4; ++r)              // redistribute alpha[4q+r]
            ap[r] = __shfl(an, q * 4 + r, 16);
    }

    float part = 0.f;
#pragma unroll
    for (int r = 0; r < 4; ++r)
        part += ap[r] * __expf(trans[STOP_ID * K + (q * 4 + r)]);
    part += __shfl_xor(part, 16, 64);
    part += __shfl_xor(part, 32, 64);
    float fwd = ls + __logf(part);
    if (lane == 0) atomicAdd(out, fwd * (1.0f / Bn));
}

// ---------------------------------------------------------------------------
// Gold score: one thread per (b, t). Subtracts gold/B from the output.
// ---------------------------------------------------------------------------
__global__ __launch_bounds__(256) void crf_gold_kernel(
    const float* __restrict__ h, const int* __restrict__ y,
    const float* __restrict__ mask, const float* __restrict__ trans,
    float* __restrict__ out)
{
    int idx = blockIdx.x * blockDim.x + threadIdx.x;   // B*T threads
    int t = idx & (Tn - 1);
    float g = 0.f;
    if (mask[idx] > 0.5f) {
        int yt = y[idx];
        int yp = (t == 0) ? START_ID : y[idx - 1];
        g = h[(size_t)idx * K + yt] + trans[yt * K + yp];
        bool last = (t == Tn - 1) || (mask[idx + 1] <= 0.5f);
        if (last) g += trans[STOP_ID * K + yt];
    }
    // wave then block reduction, one atomic per block
    float v = g;
#pragma unroll
    for (int off = 32; off; off >>= 1) v += __shfl_down(v, off, 64);
    __shared__ float red[4];
    if ((threadIdx.x & 63) == 0) red[threadIdx.x >> 6] = v;
    __syncthreads();
    if (threadIdx.x == 0) {
        float s = red[0] + red[1] + red[2] + red[3];
        atomicAdd(out, -s * (1.0f / Bn));
    }
}

extern "C" void kernel_launch(void* const* d_in, const int* in_sizes, int n_in,
                              void* d_out, int out_size, void* d_ws, size_t ws_size,
                              hipStream_t stream)
{
    const float* h     = (const float*)d_in[0];
    const int*   y     = (const int*)d_in[1];
    const float* mask  = (const float*)d_in[2];
    const float* trans = (const float*)d_in[3];
    float* out  = (float*)d_out;
    float* Pbuf = (float*)d_ws;                      // B*NCH*256 f32 = 8 MB
    float* Sbuf = Pbuf + (size_t)Bn * NCH * 256;     // B*NCH f32

    hipMemsetAsync(d_out, 0, sizeof(float), stream);
    crf_chunk_kernel<<<(Bn * NCH * 64) / 256, 256, 0, stream>>>(h, mask, trans, Pbuf, Sbuf);
    crf_gold_kernel<<<(Bn * Tn) / 256, 256, 0, stream>>>(h, y, mask, trans, out);
    crf_combine_kernel<<<(Bn * 64) / 256, 256, 0, stream>>>(Pbuf, Sbuf, trans, out);
}